// Round 6
// baseline (150.661 us; speedup 1.0000x reference)
//
#include <hip/hip_runtime.h>
#include <stdint.h>

#define NROW 8192
#define DIM  512
#define NOUT 16
#define GAMMA 0.001f
// exp(2*gamma*c) = exp2(c * 2*gamma*log2(e))
#define EXP2S (2.0f * GAMMA * 1.44269504088896340736f)
#define SC1 0x7F7F7F7F   // e8m0 scale bytes = 127 -> 2^0 = 1.0 (unit scale)

typedef __bf16 bf16_t;
typedef bf16_t bf16x4_t __attribute__((ext_vector_type(4)));
typedef bf16_t bf16x8_t __attribute__((ext_vector_type(8)));
typedef float  floatx4_t __attribute__((ext_vector_type(4)));
typedef int    intx4_t  __attribute__((ext_vector_type(4)));
typedef int    intx8_t  __attribute__((ext_vector_type(8)));

// async global->LDS, 16 B/lane. LDS dest is wave-uniform base + lane*16.
__device__ __forceinline__ void async_copy16(const void* g, const void* l) {
    __builtin_amdgcn_global_load_lds(
        (__attribute__((address_space(1))) void*)(uintptr_t)g,
        (__attribute__((address_space(3))) void*)(uint32_t)(uintptr_t)l,
        16, 0, 0);
}

// ---------- prep: fp32 -> fp8 e4m3, K-MAJOR swizzled layouts ----------------
// Row-major [r][512B] tiles in LDS have row-stride = 32 banks -> ANY b128
// frag read of 16 rows is 8-lane/slot aliased. Fix at the SOURCE: store
// per-16-row groups k-major so each frag read is 64 distinct contiguous 16B
// slots (conflict-free), and global->LDS DMA is identity/linear (coalesced).
//
// Xf slab (per 16 rows, 8192B):  [g 0..3][q 0..3][r 0..15][32B]
//   -> xg reg load lane(l15,quad): 2KB contiguous per (g,tile).
// Tf slab (per 16 rows, 8192B):  [g 0..3][u&1][u>>1 0..3][r 0..15][16B]
//   -> alo (even u): lanes hit [0,1KB) contiguous; ahi (odd u): same.
__global__ __launch_bounds__(256) void prep_convert(
    const float* __restrict__ X, const float* __restrict__ T,
    const float* __restrict__ alpha,
    uint8_t* __restrict__ Xf, uint8_t* __restrict__ Tf,
    float* __restrict__ xfac, bf16_t* __restrict__ alphaTp)
{
    const int w = threadIdx.x >> 6, lane = threadIdx.x & 63;
    const int row = blockIdx.x * 4 + w;              // 0..16383
    const bool is_test = row < NROW;
    const float* src = is_test ? X : T;
    const int r = is_test ? row : row - NROW;
    // lane owns floats [lane*8, lane*8+8) -> 8 fp8 bytes b in [lane*8, +8)
    const float4* s4 = (const float4*)(src + (size_t)r * DIM);
    const float4 v0 = s4[lane * 2];
    const float4 v1 = s4[lane * 2 + 1];
    float ss = v0.x*v0.x + v0.y*v0.y + v0.z*v0.z + v0.w*v0.w
             + v1.x*v1.x + v1.y*v1.y + v1.z*v1.z + v1.w*v1.w;
    int lo = __builtin_amdgcn_cvt_pk_fp8_f32(v0.x, v0.y, 0, false);
    lo     = __builtin_amdgcn_cvt_pk_fp8_f32(v0.z, v0.w, lo, true);
    int hi = __builtin_amdgcn_cvt_pk_fp8_f32(v1.x, v1.y, 0, false);
    hi     = __builtin_amdgcn_cvt_pk_fp8_f32(v1.z, v1.w, hi, true);
    // byte index b = lane*8 + c: g = l>>4 (128B k-groups)
    size_t off;
    if (is_test) {
        // [g][q=(l>>2)&3][r&15][32B], byte-in-32B = (l&3)*8
        off = (size_t)(r >> 4) * 8192 + ((lane >> 4) * 2048)
            + (((lane >> 2) & 3) * 512) + ((r & 15) * 32) + ((lane & 3) * 8);
        *(int2*)(Xf + off) = make_int2(lo, hi);
    } else {
        // unit u = (l>>1)&7: [g][u&1][u>>1][r&15][16B], byte-in-16B = (l&1)*8
        off = (size_t)(r >> 4) * 8192 + ((lane >> 4) * 2048)
            + (((lane >> 1) & 1) * 1024) + (((lane >> 2) & 3) * 256)
            + ((r & 15) * 16) + ((lane & 1) * 8);
        *(int2*)(Tf + off) = make_int2(lo, hi);
    }
#pragma unroll
    for (int m = 32; m > 0; m >>= 1) ss += __shfl_xor(ss, m, 64);
    const float f = __expf(-GAMMA * ss);             // all lanes hold the sum
    if (is_test) {
        if (lane == 0) xfac[r] = f;
    } else if (lane < 16) {
        // alphaT'[o][j] = exp(-g*||y_j||^2) * alpha[j][o]
        alphaTp[(size_t)lane * NROW + r] = (bf16_t)(alpha[r * 16 + lane] * f);
    }
}

// ---------- main: 4-wave blocks, wave = train64 x test64, X in 128 AGPRs ----
// r15 post-mortem: "+v" pin forced xg into ARCH VGPRs; arch demand 128(xg)
// +45(temps)+acc overflow > the ~128 arch half the compiler reserves when
// MFMA is present -> 26MB scratch spills (WRITE 8->34MB). Fix: pin xg with
// "+a" -> xg lives in a[0:127] (MFMA reads B from AGPR directly, ISA sec.10);
// arch side = acc 64 + oacc 16 + temps ~45 <= 128. Split 128/128 = the one
// the allocator wants. Everything else identical to r5 (k-major layout,
// 2 blocks/CU, conflict-free frag reads).
#define TPT 4        // train tiles per block (16 chunks x 4 tiles = 8192)
#define KLD2 72      // padded row stride (bf16) of per-wave K'' tile (64+8)

__global__ __launch_bounds__(256)
__attribute__((amdgpu_waves_per_eu(2, 2)))
void rbf_main(
    const uint8_t* __restrict__ Xf, const uint8_t* __restrict__ Tf,
    const bf16_t* __restrict__ alphaTp, const float* __restrict__ xfac,
    float* __restrict__ out)
{
    // [0,32768): T dbuf 2 x 16KB (k-major subtiled). [32768,69632): kw 4x9216.
    __shared__ __align__(16) unsigned char smem[69632];

    const int tid = threadIdx.x;
    const int w = tid >> 6, lane = tid & 63;
    const int wm = w >> 1, wn = w & 1;               // train half / test half
    const int quad = lane >> 4, l15 = lane & 15;

    const int rb = blockIdx.x;                       // 0..63  test block (XCD = rb%8)
    const int chunk = blockIdx.y;                    // 0..15  train chunk
    const int row0 = rb * 128;
    const int cb0 = chunk * (TPT * 128);

    // ---- pin X fragments: 4 k-groups x 4 tiles x 32B = 128 regs on the AGPR
    // side (asm "+a": opaque -> no remat, and out of the arch pool).
    const uint8_t* xbase = Xf + (size_t)((row0 >> 4) + wn * 4) * 8192
                              + quad * 512 + l15 * 32;
    intx8_t xg[4][4];
#pragma unroll
    for (int g = 0; g < 4; ++g)
#pragma unroll
        for (int i = 0; i < 4; ++i)
            xg[g][i] = *(const intx8_t*)(xbase + (size_t)i * 8192 + g * 2048);
#pragma unroll
    for (int g = 0; g < 4; ++g)
#pragma unroll
        for (int i = 0; i < 4; ++i)
            asm volatile("" : "+a"(xg[g][i]));       // pin in AGPRs

    // T staging: wave w stages 16-row slabs {2w, 2w+1}; 4 x 1KB DMA per g.
    const uint8_t* gT0 = Tf + (size_t)((cb0 >> 4) + 2 * w) * 8192 + lane * 16;
    const unsigned ldsT = (unsigned)(2 * w * 2048);  // wave slab base in buffer

    const floatx4_t vzero = {0.f, 0.f, 0.f, 0.f};
    floatx4_t oacc[4];
#pragma unroll
    for (int i = 0; i < 4; ++i) oacc[i] = vzero;

    bf16_t* kw = (bf16_t*)(smem + 32768 + w * 9216); // wave-private K'' region

    // prime: t=0, k-group 0 -> buf0
#pragma unroll
    for (int sj = 0; sj < 2; ++sj)
#pragma unroll
        for (int j1 = 0; j1 < 2; ++j1)
            async_copy16(gT0 + (size_t)sj * 8192 + j1 * 1024,
                         smem + ldsT + sj * 2048 + j1 * 1024);

#pragma unroll 1
    for (int t = 0; t < TPT; ++t) {
        floatx4_t acc[4][4];
#pragma unroll
        for (int i = 0; i < 4; ++i)
#pragma unroll
            for (int j = 0; j < 4; ++j) acc[i][j] = vzero;

#pragma unroll
        for (int g = 0; g < 4; ++g) {
            __syncthreads();         // buf[g&1] landed (each wave drains own vmcnt)
            if (g < 3) {             // issue g+1 into the other buffer
                const unsigned bb = ((g + 1) & 1) * 16384u;
                const size_t gofs = (size_t)t * 8 * 8192 + (g + 1) * 2048;
#pragma unroll
                for (int sj = 0; sj < 2; ++sj)
#pragma unroll
                    for (int j1 = 0; j1 < 2; ++j1)
                        async_copy16(gT0 + gofs + (size_t)sj * 8192 + j1 * 1024,
                                     smem + bb + ldsT + sj * 2048 + j1 * 1024);
            }
            const unsigned char* bufc = smem + (g & 1) * 16384;
#pragma unroll
            for (int mi = 0; mi < 4; ++mi) {
                // k-major subtile s = wm*4+mi: alo/ahi are contiguous 1KB reads
                const unsigned char* sb = bufc + (wm * 4 + mi) * 2048
                                        + quad * 256 + l15 * 16;
                const intx4_t alo = *(const intx4_t*)(sb);
                const intx4_t ahi = *(const intx4_t*)(sb + 1024);
                const intx8_t ta = __builtin_shufflevector(alo, ahi, 0, 1, 2, 3, 4, 5, 6, 7);
#pragma unroll
                for (int ni = 0; ni < 4; ++ni)
                    acc[mi][ni] = __builtin_amdgcn_mfma_scale_f32_16x16x128_f8f6f4(
                        ta, xg[g][ni], acc[mi][ni], 0, 0, 0, SC1, 0, SC1);
            }
        }

        // kw write (own region; no barrier -- in-wave lgkmcnt orders vs reads)
        // acc[mi][ni][r] = cross[train = wm*64+mi*16+quad*4+r][test = wn*64+ni*16+l15]
#pragma unroll
        for (int ni = 0; ni < 4; ++ni)
#pragma unroll
            for (int mi = 0; mi < 4; ++mi) {
                bf16x4_t pk;
#pragma unroll
                for (int r = 0; r < 4; ++r)
                    pk[r] = (bf16_t)__builtin_amdgcn_exp2f(acc[mi][ni][r] * EXP2S);
                *(bf16x4_t*)(kw + (ni * 16 + l15) * KLD2 + mi * 16 + quad * 4) = pk;
            }

        // epilogue: oacc[ni] += K''[test 16(ni) x train 64] @ alpha'[64 x 16]
        const int cb = cb0 + t * 128;
#pragma unroll
        for (int ks = 0; ks < 2; ++ks) {
            const bf16x8_t bv = *(const bf16x8_t*)(alphaTp + (size_t)l15 * NROW
                                                   + cb + wm * 64 + ks * 32 + quad * 8);
#pragma unroll
            for (int ni = 0; ni < 4; ++ni) {
                const bf16x8_t av = *(const bf16x8_t*)(kw + (ni * 16 + l15) * KLD2
                                                       + ks * 32 + quad * 8);
                oacc[ni] = __builtin_amdgcn_mfma_f32_16x16x32_bf16(av, bv, oacc[ni], 0, 0, 0);
            }
        }

        // prime next t's k-group 0 into buf0 (buf0 free: last read at g=2,
        // and all waves passed the g=3 barrier before those reads completed)
        if (t + 1 < TPT) {
            const size_t gofs = (size_t)(t + 1) * 8 * 8192;
#pragma unroll
            for (int sj = 0; sj < 2; ++sj)
#pragma unroll
                for (int j1 = 0; j1 < 2; ++j1)
                    async_copy16(gT0 + gofs + (size_t)sj * 8192 + j1 * 1024,
                                 smem + ldsT + sj * 2048 + j1 * 1024);
        }
    }

    // reduce the two train halves (wm=0,1) through LDS, then atomicAdd to out
    __syncthreads();
    float* stash = (float*)smem;
    if (wm == 1) {
#pragma unroll
        for (int ni = 0; ni < 4; ++ni)
            *(floatx4_t*)(stash + (wn * 4 + ni) * 256 + lane * 4) = oacc[ni];
    }
    __syncthreads();
    if (wm == 0) {
#pragma unroll
        for (int ni = 0; ni < 4; ++ni) {
            const floatx4_t o2 = *(const floatx4_t*)(stash + (wn * 4 + ni) * 256 + lane * 4);
            const int trow = row0 + wn * 64 + ni * 16 + quad * 4;
            const float4 xf = *(const float4*)(xfac + trow);
            atomicAdd(out + (size_t)(trow + 0) * NOUT + l15, (oacc[ni][0] + o2[0]) * xf.x);
            atomicAdd(out + (size_t)(trow + 1) * NOUT + l15, (oacc[ni][1] + o2[1]) * xf.y);
            atomicAdd(out + (size_t)(trow + 2) * NOUT + l15, (oacc[ni][2] + o2[2]) * xf.z);
            atomicAdd(out + (size_t)(trow + 3) * NOUT + l15, (oacc[ni][3] + o2[3]) * xf.w);
        }
    }
}

extern "C" void kernel_launch(void* const* d_in, const int* in_sizes, int n_in,
                              void* d_out, int out_size, void* d_ws, size_t ws_size,
                              hipStream_t stream) {
    (void)in_sizes; (void)n_in; (void)out_size; (void)ws_size;
    const float* X     = (const float*)d_in[0];
    const float* T     = (const float*)d_in[1];
    const float* alpha = (const float*)d_in[2];

    char* ws = (char*)d_ws;
    uint8_t* Xf     = (uint8_t*)ws;                                  // 4 MB
    uint8_t* Tf     = (uint8_t*)(ws + (8u << 20));                   // 4 MB
    float*   xfac   = (float*)(ws + (16u << 20));                    // 32 KB
    bf16_t*  alphaTp= (bf16_t*)(ws + (16u << 20) + (64u << 10));     // 256 KB
    float*   out    = (float*)d_out;

    hipMemsetAsync(out, 0, (size_t)NROW * NOUT * sizeof(float), stream);
    prep_convert<<<4096, 256, 0, stream>>>(X, T, alpha, Xf, Tf, xfac, alphaTp);
    dim3 grid(64, 16);   // x = rb (XCD affinity for X), y = chunk
    rbf_main<<<grid, 256, 0, stream>>>(Xf, Tf, alphaTp, xfac, out);
}

// Round 7
// 130.782 us; speedup vs baseline: 1.1520x; 1.1520x over previous
//
#include <hip/hip_runtime.h>
#include <stdint.h>

#define NROW 8192
#define DIM  512
#define NOUT 16
#define GAMMA 0.001f
// exp(2*gamma*c) = exp2(c * 2*gamma*log2(e))
#define EXP2S (2.0f * GAMMA * 1.44269504088896340736f)
#define SC1 0x7F7F7F7F   // e8m0 scale bytes = 127 -> 2^0 = 1.0 (unit scale)

typedef __bf16 bf16_t;
typedef bf16_t bf16x4_t __attribute__((ext_vector_type(4)));
typedef bf16_t bf16x8_t __attribute__((ext_vector_type(8)));
typedef float  floatx4_t __attribute__((ext_vector_type(4)));
typedef int    intx4_t  __attribute__((ext_vector_type(4)));
typedef int    intx8_t  __attribute__((ext_vector_type(8)));

// async global->LDS, 16 B/lane. LDS dest is wave-uniform base + lane*16.
__device__ __forceinline__ void async_copy16(const void* g, const void* l) {
    __builtin_amdgcn_global_load_lds(
        (__attribute__((address_space(1))) void*)(uintptr_t)g,
        (__attribute__((address_space(3))) void*)(uint32_t)(uintptr_t)l,
        16, 0, 0);
}

// ---------- prep: fp32 -> fp8 e4m3, K-MAJOR slab layouts; also zeroes out ---
// Row-major [r][512B] tiles make every b128 frag read 8-way bank-aliased
// (row stride = 32 banks). Store per-16-row slabs k-major instead so frag
// reads are 64 distinct contiguous 16B slots (conflict-free, r5-proven:
// conflicts 5.77M -> 1.57M) and DMA is identity/linear.
//
// Xf slab (16 rows, 8192B): [g 0..3][q 0..3][r 0..15][32B]
//   xg load lane(l15,quad): 32B at g*2048 + q*512 + l15*32 (2KB contig/(g,i)).
// Tf slab (16 rows, 8192B): [g 0..3][u&1][(u>>1)&3][r 0..15][16B]
//   alo: 1KB contig at g*2048 + q*256 + l15*16; ahi: +1024.
__global__ __launch_bounds__(256) void prep_convert(
    const float* __restrict__ X, const float* __restrict__ T,
    const float* __restrict__ alpha,
    uint8_t* __restrict__ Xf, uint8_t* __restrict__ Tf,
    float* __restrict__ xfac, bf16_t* __restrict__ alphaTp,
    float* __restrict__ out)
{
    // fold the output zeroing in (removes the separate memset launch)
    const int zidx = blockIdx.x * 256 + threadIdx.x;
    if (zidx < NROW * NOUT) out[zidx] = 0.f;

    const int w = threadIdx.x >> 6, lane = threadIdx.x & 63;
    const int row = blockIdx.x * 4 + w;              // 0..16383
    const bool is_test = row < NROW;
    const float* src = is_test ? X : T;
    const int r = is_test ? row : row - NROW;
    // lane owns floats [lane*8, lane*8+8) -> 8 fp8 bytes b in [lane*8, +8)
    const float4* s4 = (const float4*)(src + (size_t)r * DIM);
    const float4 v0 = s4[lane * 2];
    const float4 v1 = s4[lane * 2 + 1];
    float ss = v0.x*v0.x + v0.y*v0.y + v0.z*v0.z + v0.w*v0.w
             + v1.x*v1.x + v1.y*v1.y + v1.z*v1.z + v1.w*v1.w;
    int lo = __builtin_amdgcn_cvt_pk_fp8_f32(v0.x, v0.y, 0, false);
    lo     = __builtin_amdgcn_cvt_pk_fp8_f32(v0.z, v0.w, lo, true);
    int hi = __builtin_amdgcn_cvt_pk_fp8_f32(v1.x, v1.y, 0, false);
    hi     = __builtin_amdgcn_cvt_pk_fp8_f32(v1.z, v1.w, hi, true);
    size_t off;
    if (is_test) {
        // [g][q=(l>>2)&3][r&15][32B], byte-in-32B = (l&3)*8
        off = (size_t)(r >> 4) * 8192 + ((lane >> 4) * 2048)
            + (((lane >> 2) & 3) * 512) + ((r & 15) * 32) + ((lane & 3) * 8);
        *(int2*)(Xf + off) = make_int2(lo, hi);
    } else {
        // unit u = l>>1: [g][u&1][(u>>1)&3][r&15][16B], byte-in-16B = (l&1)*8
        off = (size_t)(r >> 4) * 8192 + ((lane >> 4) * 2048)
            + (((lane >> 1) & 1) * 1024) + (((lane >> 2) & 3) * 256)
            + ((r & 15) * 16) + ((lane & 1) * 8);
        *(int2*)(Tf + off) = make_int2(lo, hi);
    }
#pragma unroll
    for (int m = 32; m > 0; m >>= 1) ss += __shfl_xor(ss, m, 64);
    const float f = __expf(-GAMMA * ss);             // all lanes hold the sum
    if (is_test) {
        if (lane == 0) xfac[r] = f;
    } else if (lane < 16) {
        // alphaT'[o][j] = exp(-g*||y_j||^2) * alpha[j][o]
        alphaTp[(size_t)lane * NROW + r] = (bf16_t)(alpha[r * 16 + lane] * f);
    }
}

// ---------- main: 8-wave blocks, wave = train64 x test32, xg 64 regs "+v" ---
// Register reality after r1-r6: arch-VGPR side caps at ~128 with MFMA present;
// the ONLY clean pin is r4's 64-reg "+v" (VGPR=96, WRITE=8.2MB, no spill).
// r7 = r4 geometry + k-major layouts (kill conflicts) + waves_per_eu(2,4)
// (96 regs -> 4 waves/SIMD possible; (2,2) was self-capping) + kw in its own
// LDS region (69632B/block, 2 blocks/CU co-resident for barrier overlap).
#define TPT 4        // train tiles per block (16 chunks x 4 tiles = 8192)
#define KLD2 72      // padded row stride (bf16) of per-wave K'' tile (64+8)

__global__ __launch_bounds__(512)
__attribute__((amdgpu_waves_per_eu(2, 4)))
void rbf_main(
    const uint8_t* __restrict__ Xf, const uint8_t* __restrict__ Tf,
    const bf16_t* __restrict__ alphaTp, const float* __restrict__ xfac,
    float* __restrict__ out)
{
    // [0,32768): T dbuf 2 x 16KB (k-major slab chunks). [32768,69632): kw 8x4608.
    __shared__ __align__(16) unsigned char smem[69632];

    const int tid = threadIdx.x;
    const int w = tid >> 6, lane = tid & 63;
    const int wm = w >> 2, wn = w & 3;               // train half / test group
    const int quad = lane >> 4, l15 = lane & 15;

    const int rb = blockIdx.x;                       // 0..63  test block (XCD = rb%8)
    const int chunk = blockIdx.y;                    // 0..15  train chunk
    const int row0 = rb * 128;
    const int cb0 = chunk * (TPT * 128);

    // ---- pin X fragments: 4 k-groups x 2 tiles x 32B = 64 regs, "+v"
    // (r4-proven: no remat, no spill). k-major Xf: 32B contiguous per lane.
    const uint8_t* xbase = Xf + (size_t)((row0 >> 4) + wn * 2) * 8192
                              + quad * 512 + l15 * 32;
    intx8_t xg[4][2];
#pragma unroll
    for (int g = 0; g < 4; ++g)
#pragma unroll
        for (int i = 0; i < 2; ++i)
            xg[g][i] = *(const intx8_t*)(xbase + (size_t)i * 8192 + g * 2048);
#pragma unroll
    for (int g = 0; g < 4; ++g)
#pragma unroll
        for (int i = 0; i < 2; ++i)
            asm volatile("" : "+v"(xg[g][i]));       // opaque: no remat

    // T staging: wave w stages slab s=w (train rows 16w..16w+15), 2 x 1KB/g.
    // global slab chunk for (t,g): Tf[(cb0>>4 + t*8 + w)*8192 + g*2048]
    const uint8_t* gT0 = Tf + (size_t)((cb0 >> 4) + w) * 8192 + lane * 16;
    const unsigned ldsT = (unsigned)(w * 2048);      // slab base inside buffer

    const floatx4_t vzero = {0.f, 0.f, 0.f, 0.f};
    floatx4_t oacc[2];
#pragma unroll
    for (int i = 0; i < 2; ++i) oacc[i] = vzero;

    bf16_t* kw = (bf16_t*)(smem + 32768 + w * 4608); // wave-private K'' region

    // prime: t=0, k-group 0 -> buf0
#pragma unroll
    for (int j1 = 0; j1 < 2; ++j1)
        async_copy16(gT0 + j1 * 1024, smem + ldsT + j1 * 1024);

#pragma unroll 1
    for (int t = 0; t < TPT; ++t) {
        floatx4_t acc[4][2];
#pragma unroll
        for (int i = 0; i < 4; ++i)
#pragma unroll
            for (int j = 0; j < 2; ++j) acc[i][j] = vzero;

#pragma unroll
        for (int g = 0; g < 4; ++g) {
            __syncthreads();         // buf[g&1] landed (each wave drained own vmcnt)
            if (g < 3) {             // issue g+1 into the other buffer
                const unsigned bb = ((g + 1) & 1) * 16384u;
                const size_t gofs = (size_t)t * 8 * 8192 + (g + 1) * 2048;
#pragma unroll
                for (int j1 = 0; j1 < 2; ++j1)
                    async_copy16(gT0 + gofs + j1 * 1024,
                                 smem + bb + ldsT + j1 * 1024);
            }
            const unsigned char* bufc = smem + (g & 1) * 16384;
#pragma unroll
            for (int mi = 0; mi < 4; ++mi) {
                // slab s = wm*4+mi: contiguous 1KB reads, conflict-free
                const unsigned char* sb = bufc + (wm * 4 + mi) * 2048
                                        + quad * 256 + l15 * 16;
                const intx4_t alo = *(const intx4_t*)(sb);
                const intx4_t ahi = *(const intx4_t*)(sb + 1024);
                const intx8_t ta = __builtin_shufflevector(alo, ahi, 0, 1, 2, 3, 4, 5, 6, 7);
#pragma unroll
                for (int ni = 0; ni < 2; ++ni)
                    acc[mi][ni] = __builtin_amdgcn_mfma_scale_f32_16x16x128_f8f6f4(
                        ta, xg[g][ni], acc[mi][ni], 0, 0, 0, SC1, 0, SC1);
            }
        }

        // kw write (wave-private region; in-wave lgkmcnt orders write->read)
        // acc[mi][ni][r] = cross[train wm*64+mi*16+quad*4+r][test wn*32+ni*16+l15]
#pragma unroll
        for (int ni = 0; ni < 2; ++ni)
#pragma unroll
            for (int mi = 0; mi < 4; ++mi) {
                bf16x4_t pk;
#pragma unroll
                for (int r = 0; r < 4; ++r)
                    pk[r] = (bf16_t)__builtin_amdgcn_exp2f(acc[mi][ni][r] * EXP2S);
                *(bf16x4_t*)(kw + (ni * 16 + l15) * KLD2 + mi * 16 + quad * 4) = pk;
            }

        // epilogue: oacc[ni] += K''[test 16(ni) x train 64] @ alpha'[64 x 16]
        const int cb = cb0 + t * 128;
#pragma unroll
        for (int ks = 0; ks < 2; ++ks) {
            const bf16x8_t bv = *(const bf16x8_t*)(alphaTp + (size_t)l15 * NROW
                                                   + cb + wm * 64 + ks * 32 + quad * 8);
#pragma unroll
            for (int ni = 0; ni < 2; ++ni) {
                const bf16x8_t av = *(const bf16x8_t*)(kw + (ni * 16 + l15) * KLD2
                                                       + ks * 32 + quad * 8);
                oacc[ni] = __builtin_amdgcn_mfma_f32_16x16x32_bf16(av, bv, oacc[ni], 0, 0, 0);
            }
        }

        // prime next t's k-group 0 into buf0 (all waves' buf0 reads drained
        // at the g=3 barrier; landing guaranteed by next t's g=0 barrier)
        if (t + 1 < TPT) {
            const size_t gofs = (size_t)(t + 1) * 8 * 8192;
#pragma unroll
            for (int j1 = 0; j1 < 2; ++j1)
                async_copy16(gT0 + gofs + j1 * 1024,
                             smem + ldsT + j1 * 1024);
        }
    }

    // reduce the two train halves (wm=0,1) through LDS, then atomicAdd to out
    __syncthreads();
    float* stash = (float*)smem;
    if (wm == 1) {
#pragma unroll
        for (int ni = 0; ni < 2; ++ni)
            *(floatx4_t*)(stash + (wn * 2 + ni) * 256 + lane * 4) = oacc[ni];
    }
    __syncthreads();
    if (wm == 0) {
#pragma unroll
        for (int ni = 0; ni < 2; ++ni) {
            const floatx4_t o2 = *(const floatx4_t*)(stash + (wn * 2 + ni) * 256 + lane * 4);
            const int trow = row0 + wn * 32 + ni * 16 + quad * 4;
            const float4 xf = *(const float4*)(xfac + trow);
            atomicAdd(out + (size_t)(trow + 0) * NOUT + l15, (oacc[ni][0] + o2[0]) * xf.x);
            atomicAdd(out + (size_t)(trow + 1) * NOUT + l15, (oacc[ni][1] + o2[1]) * xf.y);
            atomicAdd(out + (size_t)(trow + 2) * NOUT + l15, (oacc[ni][2] + o2[2]) * xf.z);
            atomicAdd(out + (size_t)(trow + 3) * NOUT + l15, (oacc[ni][3] + o2[3]) * xf.w);
        }
    }
}

extern "C" void kernel_launch(void* const* d_in, const int* in_sizes, int n_in,
                              void* d_out, int out_size, void* d_ws, size_t ws_size,
                              hipStream_t stream) {
    (void)in_sizes; (void)n_in; (void)out_size; (void)ws_size;
    const float* X     = (const float*)d_in[0];
    const float* T     = (const float*)d_in[1];
    const float* alpha = (const float*)d_in[2];

    char* ws = (char*)d_ws;
    uint8_t* Xf     = (uint8_t*)ws;                                  // 4 MB
    uint8_t* Tf     = (uint8_t*)(ws + (8u << 20));                   // 4 MB
    float*   xfac   = (float*)(ws + (16u << 20));                    // 32 KB
    bf16_t*  alphaTp= (bf16_t*)(ws + (16u << 20) + (64u << 10));     // 256 KB
    float*   out    = (float*)d_out;

    prep_convert<<<4096, 256, 0, stream>>>(X, T, alpha, Xf, Tf, xfac, alphaTp, out);
    dim3 grid(64, 16);   // x = rb (XCD affinity for X), y = chunk
    rbf_main<<<grid, 512, 0, stream>>>(Xf, Tf, alphaTp, xfac, out);
}